// Round 11
// baseline (309.422 us; speedup 1.0000x reference)
//
#include <hip/hip_runtime.h>
#include <hip/hip_fp16.h>
#include <cstdint>
#include <cstddef>

#define BN_EPS 1e-5f
#define NBLK 256   // blocks for edge-chunk kernels

typedef _Float16 f16x8 __attribute__((ext_vector_type(8)));
typedef float f32x4 __attribute__((ext_vector_type(4)));
typedef unsigned int u32x2 __attribute__((ext_vector_type(2)));
typedef unsigned int u32x4 __attribute__((ext_vector_type(4)));

__device__ __forceinline__ int ld_src(const int* e, int E, int i, int is64) {
    return is64 ? e[2 * i] : e[i];
}
__device__ __forceinline__ int ld_dst(const int* e, int E, int i, int is64) {
    return is64 ? e[2 * (E + i)] : e[E + i];
}

// per-block int64 detection: odd 32-bit words of this block's chunk all zero => int64
__device__ __forceinline__ int detect64(const int* __restrict__ e, int e0, int e1, int t, int* det) {
    if (t == 0) *det = 0;
    __syncthreads();
    int probe = 0;
    int lim = min(e1, e0 + 2048);
    for (int i = e0 + t; i < lim; i += 256) probe |= e[2 * i + 1];
    atomicOr(det, probe);
    __syncthreads();
    return (*det == 0);
}

// ---------- stage 1: per-block coarse-bucket counts (LDS only) ----------
__global__ __launch_bounds__(256) void k_bcount(const int* __restrict__ e, int* __restrict__ cntMat,
                                                int E, int nbC) {
    __shared__ int c[512];
    __shared__ int det;
    const int t = threadIdx.x, blk = blockIdx.x;
    for (int b = t; b < nbC; b += 256) c[b] = 0;
    const int chunk = (E + NBLK - 1) / NBLK;
    const int e0 = blk * chunk;
    const int e1 = min(E, e0 + chunk);
    const int is64 = detect64(e, e0, e1, t, &det);   // includes syncthreads
    for (int i = e0 + t; i < e1; i += 256) {
        int d = ld_dst(e, E, i, is64);
        atomicAdd(&c[d >> 9], 1);
    }
    __syncthreads();
    for (int b = t; b < nbC; b += 256) cntMat[b * NBLK + blk] = c[b];
}

// ---------- hierarchical exclusive scan over M elements ----------
__global__ __launch_bounds__(256) void k_scan1(const int* __restrict__ in, int* __restrict__ outp,
                                               int* __restrict__ blockSums, int M) {
    __shared__ int sh[256];
    const int t = threadIdx.x;
    const int base = blockIdx.x * 1024 + t * 4;
    int v[4];
#pragma unroll
    for (int i = 0; i < 4; ++i) v[i] = (base + i < M) ? in[base + i] : 0;
    int tot = v[0] + v[1] + v[2] + v[3];
    sh[t] = tot;
    __syncthreads();
    int val = tot;
    for (int o = 1; o < 256; o <<= 1) {
        int x = (t >= o) ? sh[t - o] : 0;
        __syncthreads();
        val += x;
        sh[t] = val;
        __syncthreads();
    }
    int run = val - tot;
#pragma unroll
    for (int i = 0; i < 4; ++i) {
        if (base + i < M) outp[base + i] = run;
        run += v[i];
    }
    if (t == 255) blockSums[blockIdx.x] = val;
}

// scan2 also zeroes BN stats (idle-thread work; runs long before stats accumulate)
__global__ __launch_bounds__(256) void k_scan2(int* __restrict__ blockSums, int nB,
                                               float* __restrict__ stats1, float* __restrict__ stats2) {
    __shared__ int sh[256];
    const int t = threadIdx.x;
    stats1[t] = 0.0f;
    if (t < 128) stats2[t] = 0.0f;
    const int base = t * 4;
    int v[4];
#pragma unroll
    for (int i = 0; i < 4; ++i) v[i] = (base + i < nB) ? blockSums[base + i] : 0;
    int tot = v[0] + v[1] + v[2] + v[3];
    sh[t] = tot;
    __syncthreads();
    int val = tot;
    for (int o = 1; o < 256; o <<= 1) {
        int x = (t >= o) ? sh[t - o] : 0;
        __syncthreads();
        val += x;
        sh[t] = val;
        __syncthreads();
    }
    int run = val - tot;
#pragma unroll
    for (int i = 0; i < 4; ++i) {
        if (base + i < nB) blockSums[base + i] = run;
        run += v[i];
    }
}

// ---------- stage 3: scatter packed (dstLocal,src) into bucket-major pairBuf ----------
__global__ __launch_bounds__(256) void k_bscatter(const int* __restrict__ e,
                                                  const int* __restrict__ ofsMat, const int* __restrict__ blockSums,
                                                  unsigned* __restrict__ pairBuf, int E, int nbC) {
    __shared__ int ofs[512];
    __shared__ int det;
    const int t = threadIdx.x, blk = blockIdx.x;
    for (int b = t; b < nbC; b += 256) {
        int idx = b * NBLK + blk;
        ofs[b] = ofsMat[idx] + blockSums[idx >> 10];
    }
    const int chunk = (E + NBLK - 1) / NBLK;
    const int e0 = blk * chunk;
    const int e1 = min(E, e0 + chunk);
    const int is64 = detect64(e, e0, e1, t, &det);
    for (int i = e0 + t; i < e1; i += 256) {
        int s = ld_src(e, E, i, is64);
        int d = ld_dst(e, E, i, is64);
        int pos = atomicAdd(&ofs[d >> 9], 1);
        pairBuf[pos] = ((unsigned)(d & 511) << 23) | (unsigned)s;
    }
}

// ---------- stage 4: per-bucket fine counting sort; writes csrSrc, rowPtr, cnt, dinv ----------
__global__ __launch_bounds__(256) void k_fsort(const unsigned* __restrict__ pairBuf, const int* __restrict__ ofsMat,
                                               const int* __restrict__ blockSums,
                                               int* __restrict__ csrSrc, int* __restrict__ rowPtr,
                                               int* __restrict__ cnt, float* __restrict__ dinv,
                                               int E, int N, int nbC) {
    __shared__ int hist[512];
    __shared__ int lofs[512];
    __shared__ int sc[256];
    const int t = threadIdx.x, b = blockIdx.x;
    const int i0 = b * NBLK;
    const int lo = ofsMat[i0] + blockSums[i0 >> 10];
    int hi = E;
    if (b + 1 < nbC) {
        const int i1 = (b + 1) * NBLK;
        hi = ofsMat[i1] + blockSums[i1 >> 10];
    }
    hist[t] = 0; hist[t + 256] = 0;
    __syncthreads();
    for (int i = lo + t; i < hi; i += 256) atomicAdd(&hist[pairBuf[i] >> 23], 1);
    __syncthreads();
    int v0 = hist[2 * t], v1 = hist[2 * t + 1];
    int tot = v0 + v1;
    sc[t] = tot;
    __syncthreads();
    int val = tot;
    for (int o = 1; o < 256; o <<= 1) {
        int x = (t >= o) ? sc[t - o] : 0;
        __syncthreads();
        val += x;
        sc[t] = val;
        __syncthreads();
    }
    int excl = val - tot;
    const int d0 = b * 512 + 2 * t;
    const int d1 = d0 + 1;
    lofs[2 * t] = lo + excl;
    lofs[2 * t + 1] = lo + excl + v0;
    if (d0 < N) { rowPtr[d0] = lo + excl;      cnt[d0] = v0; dinv[d0] = rsqrtf((float)(v0 + 1)); }
    if (d1 < N) { rowPtr[d1] = lo + excl + v0; cnt[d1] = v1; dinv[d1] = rsqrtf((float)(v1 + 1)); }
    __syncthreads();
    for (int i = lo + t; i < hi; i += 256) {
        unsigned p = pairBuf[i];
        int dL = p >> 23;
        int s = (int)(p & 0x7FFFFFu);
        int pos = atomicAdd(&lofs[dL], 1);
        csrSrc[pos] = s;
    }
}

// ---------- GEMM1 (MFMA fp16): hs1 = (x @ W1) * dinv[row] ----------
__global__ __launch_bounds__(256, 2) void k_gemm1(const float* __restrict__ x, const float* __restrict__ W,
                                                  const float* __restrict__ dinv,
                                                  _Float16* __restrict__ hs1, int N) {
    __shared__ _Float16 Ws[128][136];
    __shared__ _Float16 xs[128][136];
    const int t = threadIdx.x;
    const int row0 = blockIdx.x * 128;

#pragma unroll
    for (int i = 0; i < 16; ++i) {
        int j = t + i * 256;
        int k = j >> 5, c = (j & 31) << 2;
        float4 v = ((const float4*)W)[j];
        union { _Float16 h[4]; uint2 u; } p;
        p.h[0] = (_Float16)v.x; p.h[1] = (_Float16)v.y; p.h[2] = (_Float16)v.z; p.h[3] = (_Float16)v.w;
        *(uint2*)&Ws[k][c] = p.u;
    }
#pragma unroll
    for (int i = 0; i < 16; ++i) {
        int j = t + i * 256;
        int r = j >> 5, c = (j & 31) << 2;
        int gr = row0 + r;
        f32x4 v = (f32x4)(0.f);
        if (gr < N) v = __builtin_nontemporal_load((const f32x4*)&x[(size_t)gr * 128 + c]);
        union { _Float16 h[4]; uint2 u; } p;
        p.h[0] = (_Float16)v[0]; p.h[1] = (_Float16)v[1]; p.h[2] = (_Float16)v[2]; p.h[3] = (_Float16)v[3];
        *(uint2*)&xs[r][c] = p.u;
    }
    __syncthreads();

    const int w = t >> 6, l = t & 63;
    const int wm = w >> 1, wn = w & 1;
    const int l15 = l & 15, lg = l >> 4;

    f16x8 bfr[4][4];   // [nt][ks]
#pragma unroll
    for (int nt = 0; nt < 4; ++nt)
#pragma unroll
        for (int ks = 0; ks < 4; ++ks) {
            int col = wn * 64 + nt * 16 + l15;
            int kb = ks * 32 + lg * 8;
            f16x8 b;
#pragma unroll
            for (int j = 0; j < 8; ++j) b[j] = Ws[kb + j][col];
            bfr[nt][ks] = b;
        }

    f32x4 acc[4][4];
#pragma unroll
    for (int mt = 0; mt < 4; ++mt)
#pragma unroll
        for (int nt = 0; nt < 4; ++nt) acc[mt][nt] = (f32x4)(0.f);

#pragma unroll
    for (int mt = 0; mt < 4; ++mt) {
        const int r = wm * 64 + mt * 16 + l15;
        f16x8 afr[4];
#pragma unroll
        for (int ks = 0; ks < 4; ++ks) afr[ks] = *(const f16x8*)&xs[r][ks * 32 + lg * 8];
#pragma unroll
        for (int nt = 0; nt < 4; ++nt)
#pragma unroll
            for (int ks = 0; ks < 4; ++ks)
                acc[mt][nt] = __builtin_amdgcn_mfma_f32_16x16x32_f16(afr[ks], bfr[nt][ks], acc[mt][nt], 0, 0, 0);
    }

#pragma unroll
    for (int mt = 0; mt < 4; ++mt) {
        const int rbase = row0 + wm * 64 + mt * 16 + lg * 4;
#pragma unroll
        for (int rr = 0; rr < 4; ++rr) {
            int gr = rbase + rr;
            if (gr < N) {
                float dv = dinv[gr];
#pragma unroll
                for (int nt = 0; nt < 4; ++nt) {
                    int col = wn * 64 + nt * 16 + l15;
                    hs1[(size_t)gr * 128 + col] = (_Float16)(acc[mt][nt][rr] * dv);
                }
            }
        }
    }
}

// ---------- gather128: wave per node, lane = half2 slot; 16/8/4/1 unroll cascade ----------
__global__ __launch_bounds__(256) void k_gather128(const int* __restrict__ csrSrc, const int* __restrict__ rowPtr,
                                                   const int* __restrict__ cnt, const float* __restrict__ dinv,
                                                   const __half2* __restrict__ hs, __half2* __restrict__ agg, int N) {
    int wv = (blockIdx.x * 256 + threadIdx.x) >> 6;
    if (wv >= N) return;
    const int d = __builtin_amdgcn_readfirstlane(wv);
    const int lane = threadIdx.x & 63;
    const size_t fo = (size_t)d * 64 + lane;
    float2 acc = __half22float2(hs[fo]);   // self loop
    const int start = __builtin_amdgcn_readfirstlane(rowPtr[d]);
    const int c = __builtin_amdgcn_readfirstlane(cnt[d]);
    const int* __restrict__ p = csrSrc + start;
    int j = 0;
    for (; j + 15 < c; j += 16) {   // 16 row-loads in flight
        int s[16];
#pragma unroll
        for (int u = 0; u < 16; ++u) s[u] = p[j + u];
        float2 v[16];
#pragma unroll
        for (int u = 0; u < 16; ++u) v[u] = __half22float2(hs[(size_t)s[u] * 64 + lane]);
#pragma unroll
        for (int u = 0; u < 16; ++u) { acc.x += v[u].x; acc.y += v[u].y; }
    }
    for (; j + 7 < c; j += 8) {
        float2 v[8];
#pragma unroll
        for (int u = 0; u < 8; ++u) v[u] = __half22float2(hs[(size_t)p[j + u] * 64 + lane]);
#pragma unroll
        for (int u = 0; u < 8; ++u) { acc.x += v[u].x; acc.y += v[u].y; }
    }
    for (; j + 3 < c; j += 4) {
        float2 v[4];
#pragma unroll
        for (int u = 0; u < 4; ++u) v[u] = __half22float2(hs[(size_t)p[j + u] * 64 + lane]);
#pragma unroll
        for (int u = 0; u < 4; ++u) { acc.x += v[u].x; acc.y += v[u].y; }
    }
    for (; j < c; ++j) {
        float2 v = __half22float2(hs[(size_t)p[j] * 64 + lane]);
        acc.x += v.x; acc.y += v.y;
    }
    const float wgt = dinv[d];
    union { __half2 h; unsigned int u; } o;
    o.h = __floats2half2_rn(acc.x * wgt, acc.y * wgt);
    __builtin_nontemporal_store(o.u, (unsigned int*)&agg[fo]);
}

// ---------- gather64: 8 lane-groups per neighbor row (128B), dwordx4 loads ----------
__global__ __launch_bounds__(256) void k_gather64(const int* __restrict__ csrSrc, const int* __restrict__ rowPtr,
                                                  const int* __restrict__ cnt, const float* __restrict__ dinv,
                                                  const __half2* __restrict__ hs, __half2* __restrict__ agg, int N) {
    int wv = (blockIdx.x * 256 + threadIdx.x) >> 6;
    if (wv >= N) return;
    const int d = __builtin_amdgcn_readfirstlane(wv);
    const int l = threadIdx.x & 63;
    const int g = l >> 3, f = l & 7;   // 8 groups of 8 lanes; row = 32 half2 = 8 lanes x 16B

    float2 acc[4];
    if (g == 0) {
        union { uint4 u; __half2 h[4]; } v;
        v.u = *(const uint4*)&hs[(size_t)d * 32 + f * 4];
#pragma unroll
        for (int i = 0; i < 4; ++i) acc[i] = __half22float2(v.h[i]);
    } else {
#pragma unroll
        for (int i = 0; i < 4; ++i) acc[i] = make_float2(0.f, 0.f);
    }

    const int start = __builtin_amdgcn_readfirstlane(rowPtr[d]);
    const int c = __builtin_amdgcn_readfirstlane(cnt[d]);
    const int* __restrict__ p = csrSrc + start;
    int j = 0;
    for (; j + 15 < c; j += 16) {   // 16 neighbors: 2 uint4 loads in flight per lane
        int s0 = p[j + g], s1 = p[j + 8 + g];
        union { uint4 u; __half2 h[4]; } v0, v1;
        v0.u = *(const uint4*)&hs[(size_t)s0 * 32 + f * 4];
        v1.u = *(const uint4*)&hs[(size_t)s1 * 32 + f * 4];
#pragma unroll
        for (int i = 0; i < 4; ++i) {
            float2 a = __half22float2(v0.h[i]);
            float2 b = __half22float2(v1.h[i]);
            acc[i].x += a.x + b.x;
            acc[i].y += a.y + b.y;
        }
    }
    for (; j < c; j += 8) {         // predicated tail, 8 neighbors at a time
        int idx = j + g;
        if (idx < c) {
            union { uint4 u; __half2 h[4]; } v;
            v.u = *(const uint4*)&hs[(size_t)p[idx] * 32 + f * 4];
#pragma unroll
            for (int i = 0; i < 4; ++i) {
                float2 a = __half22float2(v.h[i]);
                acc[i].x += a.x;
                acc[i].y += a.y;
            }
        }
    }

#pragma unroll
    for (int i = 0; i < 4; ++i) {
        acc[i].x += __shfl_xor(acc[i].x, 8);
        acc[i].y += __shfl_xor(acc[i].y, 8);
        acc[i].x += __shfl_xor(acc[i].x, 16);
        acc[i].y += __shfl_xor(acc[i].y, 16);
        acc[i].x += __shfl_xor(acc[i].x, 32);
        acc[i].y += __shfl_xor(acc[i].y, 32);
    }

    if (g == 0) {
        const float wgt = dinv[d];
        union { u32x4 u; __half2 h[4]; } o;
#pragma unroll
        for (int i = 0; i < 4; ++i) o.h[i] = __floats2half2_rn(acc[i].x * wgt, acc[i].y * wgt);
        __builtin_nontemporal_store(o.u, (u32x4*)&agg[(size_t)d * 32 + f * 4]);
    }
}

// ---------- BN stats from fp16 agg: per-feature sum & sumsq ----------
template <int F>
__global__ __launch_bounds__(256) void k_stats_h(const __half2* __restrict__ a, float* __restrict__ stats, int N) {
    const int S = F / 2;
    const int t = threadIdx.x;
    const int slot = t & (S - 1);
    const int sub = t / S;
    const int rpb = 256 / S;
    float sx = 0.f, sy = 0.f, qx = 0.f, qy = 0.f;
    for (int r = blockIdx.x * rpb + sub; r < N; r += gridDim.x * rpb) {
        float2 v = __half22float2(a[(size_t)r * S + slot]);
        sx += v.x; sy += v.y;
        qx += v.x * v.x; qy += v.y * v.y;
    }
    __shared__ float l0[256], l1[256], l2[256], l3[256];
    l0[t] = sx; l1[t] = sy; l2[t] = qx; l3[t] = qy;
    __syncthreads();
    if (t < S) {
#pragma unroll
        for (int i = 1; i < rpb; ++i) {
            sx += l0[t + i * S]; sy += l1[t + i * S];
            qx += l2[t + i * S]; qy += l3[t + i * S];
        }
        atomicAdd(&stats[2 * t], sx);
        atomicAdd(&stats[2 * t + 1], sy);
        atomicAdd(&stats[F + 2 * t], qx);
        atomicAdd(&stats[F + 2 * t + 1], qy);
    }
}

__global__ void k_bnparam(const float* __restrict__ stats, const float* __restrict__ g, const float* __restrict__ be,
                          float* __restrict__ ss, int N, int F) {
    int f = threadIdx.x;
    if (f < F) {
        float invN = 1.0f / (float)N;
        float mean = stats[f] * invN;
        float var = stats[F + f] * invN - mean * mean;
        var = fmaxf(var, 0.f);
        float inv = rsqrtf(var + BN_EPS);
        float scale = g[f] * inv;
        ss[f] = scale;
        ss[F + f] = be[f] - mean * scale;
    }
}

// ---------- GEMM2 (MFMA fp16): hs2 = (relu(bn(agg1_fp16)) @ W2) * dinv[row] ----------
__global__ __launch_bounds__(256, 2) void k_gemm2(const __half* __restrict__ a_in, const float* __restrict__ W,
                                                  const float* __restrict__ ss, const float* __restrict__ dinv,
                                                  _Float16* __restrict__ hs2, int N) {
    __shared__ _Float16 Ws[128][72];
    __shared__ _Float16 xs[128][136];
    const int t = threadIdx.x;
    const int row0 = blockIdx.x * 128;

#pragma unroll
    for (int i = 0; i < 8; ++i) {
        int j = t + i * 256;
        int k = j >> 4, c = (j & 15) << 2;
        float4 v = ((const float4*)W)[j];
        union { _Float16 h[4]; uint2 u; } p;
        p.h[0] = (_Float16)v.x; p.h[1] = (_Float16)v.y; p.h[2] = (_Float16)v.z; p.h[3] = (_Float16)v.w;
        *(uint2*)&Ws[k][c] = p.u;
    }
#pragma unroll
    for (int i = 0; i < 16; ++i) {
        int j = t + i * 256;
        int r = j >> 5, c = (j & 31) << 2;
        int gr = row0 + r;
        float4 v = make_float4(0.f, 0.f, 0.f, 0.f);
        if (gr < N) {
            union { u32x2 u; __half2 h[2]; } iv;
            iv.u = __builtin_nontemporal_load((const u32x2*)&a_in[(size_t)gr * 128 + c]);
            float2 v01 = __half22float2(iv.h[0]);
            float2 v23 = __half22float2(iv.h[1]);
            float4 sc = *(const float4*)&ss[c];
            float4 sh = *(const float4*)&ss[128 + c];
            v.x = fmaxf(0.f, fmaf(v01.x, sc.x, sh.x));
            v.y = fmaxf(0.f, fmaf(v01.y, sc.y, sh.y));
            v.z = fmaxf(0.f, fmaf(v23.x, sc.z, sh.z));
            v.w = fmaxf(0.f, fmaf(v23.y, sc.w, sh.w));
        }
        union { _Float16 h[4]; uint2 u; } p;
        p.h[0] = (_Float16)v.x; p.h[1] = (_Float16)v.y; p.h[2] = (_Float16)v.z; p.h[3] = (_Float16)v.w;
        *(uint2*)&xs[r][c] = p.u;
    }
    __syncthreads();

    const int w = t >> 6, l = t & 63;
    const int wm = w >> 1, wn = w & 1;
    const int l15 = l & 15, lg = l >> 4;

    f16x8 bfr[2][4];
#pragma unroll
    for (int nt = 0; nt < 2; ++nt)
#pragma unroll
        for (int ks = 0; ks < 4; ++ks) {
            int col = wn * 32 + nt * 16 + l15;
            int kb = ks * 32 + lg * 8;
            f16x8 b;
#pragma unroll
            for (int j = 0; j < 8; ++j) b[j] = Ws[kb + j][col];
            bfr[nt][ks] = b;
        }

    f32x4 acc[4][2];
#pragma unroll
    for (int mt = 0; mt < 4; ++mt)
#pragma unroll
        for (int nt = 0; nt < 2; ++nt) acc[mt][nt] = (f32x4)(0.f);

#pragma unroll
    for (int mt = 0; mt < 4; ++mt) {
        const int r = wm * 64 + mt * 16 + l15;
        f16x8 afr[4];
#pragma unroll
        for (int ks = 0; ks < 4; ++ks) afr[ks] = *(const f16x8*)&xs[r][ks * 32 + lg * 8];
#pragma unroll
        for (int nt = 0; nt < 2; ++nt)
#pragma unroll
            for (int ks = 0; ks < 4; ++ks)
                acc[mt][nt] = __builtin_amdgcn_mfma_f32_16x16x32_f16(afr[ks], bfr[nt][ks], acc[mt][nt], 0, 0, 0);
    }

#pragma unroll
    for (int mt = 0; mt < 4; ++mt) {
        const int rbase = row0 + wm * 64 + mt * 16 + lg * 4;
#pragma unroll
        for (int rr = 0; rr < 4; ++rr) {
            int gr = rbase + rr;
            if (gr < N) {
                float dv = dinv[gr];
#pragma unroll
                for (int nt = 0; nt < 2; ++nt) {
                    int col = wn * 32 + nt * 16 + l15;
                    hs2[(size_t)gr * 64 + col] = (_Float16)(acc[mt][nt][rr] * dv);
                }
            }
        }
    }
}

// ---------- final: out = relu(bn(agg2_fp16)) @ Wf + bf ----------
__global__ __launch_bounds__(256) void k_final(const __half* __restrict__ a_in, const float* __restrict__ ss,
                                               const float* __restrict__ Wf, const float* __restrict__ bf,
                                               float* __restrict__ out, int N) {
    __shared__ float buf[256][65];
    const int t = threadIdx.x;
    const int row0 = blockIdx.x * 256;

#pragma unroll
    for (int i = 0; i < 16; ++i) {
        int j = t + i * 256;
        int r = j >> 4;
        int k = (j & 15) << 2;
        float4 v = make_float4(0.f, 0.f, 0.f, 0.f);
        int gr = row0 + r;
        if (gr < N) {
            union { u32x2 u; __half2 h[2]; } iv;
            iv.u = __builtin_nontemporal_load((const u32x2*)&a_in[(size_t)gr * 64 + k]);
            float2 v01 = __half22float2(iv.h[0]);
            float2 v23 = __half22float2(iv.h[1]);
            float4 sc = *(const float4*)&ss[k];
            float4 sh = *(const float4*)&ss[64 + k];
            v.x = fmaxf(0.f, fmaf(v01.x, sc.x, sh.x));
            v.y = fmaxf(0.f, fmaf(v01.y, sc.y, sh.y));
            v.z = fmaxf(0.f, fmaf(v23.x, sc.z, sh.z));
            v.w = fmaxf(0.f, fmaf(v23.y, sc.w, sh.w));
        }
        buf[r][k + 0] = v.x; buf[r][k + 1] = v.y; buf[r][k + 2] = v.z; buf[r][k + 3] = v.w;
    }
    __syncthreads();

    int gr = row0 + t;
    if (gr < N) {
        float a0 = 0.f, a1 = 0.f;
        for (int k = 0; k < 64; ++k) {
            float v = buf[t][k];
            a0 = fmaf(v, Wf[2 * k + 0], a0);
            a1 = fmaf(v, Wf[2 * k + 1], a1);
        }
        out[(size_t)gr * 2 + 0] = a0 + bf[0];
        out[(size_t)gr * 2 + 1] = a1 + bf[1];
    }
}

extern "C" void kernel_launch(void* const* d_in, const int* in_sizes, int n_in,
                              void* d_out, int out_size, void* d_ws, size_t ws_size,
                              hipStream_t stream) {
    const float* x   = (const float*)d_in[0];
    const int*   ei  = (const int*)d_in[1];
    const float* W1  = (const float*)d_in[2];
    const float* g1  = (const float*)d_in[4];
    const float* be1 = (const float*)d_in[5];
    const float* W2  = (const float*)d_in[6];
    const float* g2  = (const float*)d_in[8];
    const float* be2 = (const float*)d_in[9];
    const float* Wf  = (const float*)d_in[10];
    const float* bf  = (const float*)d_in[11];
    float* out = (float*)d_out;

    const int N = in_sizes[0] / 128;
    const int E = in_sizes[1] / 2;
    const int nbC = (N + 511) >> 9;          // coarse buckets of 512 dsts
    const int M = nbC * NBLK;                // count-matrix size
    const int nBs = (M + 1023) / 1024;       // scan blocks (<=1024 fits k_scan2)

    float* fws = (float*)d_ws;
    float* stats1 = fws + 64;            // 256
    float* stats2 = fws + 320;           // 128
    float* ss1    = fws + 448;           // 256
    float* ss2    = fws + 704;           // 128
    int*   blockSums = (int*)(fws + 832);// up to 1024

    const size_t Na = (size_t)((N + 255) & ~255);
    const size_t Ea = (size_t)((E + 255) & ~255);
    const size_t Ma = (size_t)((M + 255) & ~255);
    size_t off = 2048;
    int*   cnt    = (int*)(fws + off);  off += Na;
    int*   rowPtr = (int*)(fws + off);  off += Na;
    float* dinv   = fws + off;          off += Na;
    int*   cntMat = (int*)(fws + off);  off += Ma;
    int*   ofsMat = (int*)(fws + off);  off += Ma;
    int*   csrSrc = (int*)(fws + off);  off += Ea;
    _Float16* hs1 = (_Float16*)(fws + off);                // N*128 fp16
    __half*  agg1 = (__half*)(fws + off + (size_t)N * 64); // N*128 fp16
    _Float16* hs2 = hs1;                                   // N*64 fp16 (reuse)
    __half*  agg2 = agg1;                                  // N*64 fp16 (reuse)
    unsigned* pairBuf = (unsigned*)hs1;                    // E u32 (dead before gemm1)

    // atomic-free CSR build (two-level counting sort); per-block int64 self-detection
    k_bcount<<<NBLK, 256, 0, stream>>>(ei, cntMat, E, nbC);
    k_scan1<<<nBs, 256, 0, stream>>>(cntMat, ofsMat, blockSums, M);
    k_scan2<<<1, 256, 0, stream>>>(blockSums, nBs, stats1, stats2);
    k_bscatter<<<NBLK, 256, 0, stream>>>(ei, ofsMat, blockSums, pairBuf, E, nbC);
    k_fsort<<<nbC, 256, 0, stream>>>(pairBuf, ofsMat, blockSums, csrSrc, rowPtr, cnt, dinv, E, N, nbC);

    k_gemm1<<<(N + 127) / 128, 256, 0, stream>>>(x, W1, dinv, hs1, N);
    k_gather128<<<(N * 64 + 255) / 256, 256, 0, stream>>>(csrSrc, rowPtr, cnt, dinv,
                                                          (const __half2*)hs1, (__half2*)agg1, N);
    k_stats_h<128><<<512, 256, 0, stream>>>((const __half2*)agg1, stats1, N);
    k_bnparam<<<1, 128, 0, stream>>>(stats1, g1, be1, ss1, N, 128);

    k_gemm2<<<(N + 127) / 128, 256, 0, stream>>>(agg1, W2, ss1, dinv, hs2, N);
    k_gather64<<<(N * 64 + 255) / 256, 256, 0, stream>>>(csrSrc, rowPtr, cnt, dinv,
                                                         (const __half2*)hs2, (__half2*)agg2, N);
    k_stats_h<64><<<512, 256, 0, stream>>>((const __half2*)agg2, stats2, N);
    k_bnparam<<<1, 128, 0, stream>>>(stats2, g2, be2, ss2, N, 64);

    k_final<<<(N + 255) / 256, 256, 0, stream>>>(agg2, ss2, Wf, bf, out, N);
}

// Round 12
// 290.540 us; speedup vs baseline: 1.0650x; 1.0650x over previous
//
#include <hip/hip_runtime.h>
#include <hip/hip_fp16.h>
#include <cstdint>
#include <cstddef>

#define BN_EPS 1e-5f
#define NBLK 256   // blocks for edge-chunk kernels

typedef _Float16 f16x8 __attribute__((ext_vector_type(8)));
typedef float f32x4 __attribute__((ext_vector_type(4)));

__device__ __forceinline__ int ld_src(const int* e, int E, int i, int is64) {
    return is64 ? e[2 * i] : e[i];
}
__device__ __forceinline__ int ld_dst(const int* e, int E, int i, int is64) {
    return is64 ? e[2 * (E + i)] : e[E + i];
}

// per-block int64 detection: odd 32-bit words of this block's chunk all zero => int64
__device__ __forceinline__ int detect64(const int* __restrict__ e, int e0, int e1, int t, int* det) {
    if (t == 0) *det = 0;
    __syncthreads();
    int probe = 0;
    int lim = min(e1, e0 + 2048);
    for (int i = e0 + t; i < lim; i += 256) probe |= e[2 * i + 1];
    atomicOr(det, probe);
    __syncthreads();
    return (*det == 0);
}

// ---------- stage 1: per-block coarse-bucket counts (LDS only) ----------
__global__ __launch_bounds__(256) void k_bcount(const int* __restrict__ e, int* __restrict__ cntMat,
                                                int E, int nbC) {
    __shared__ int c[512];
    __shared__ int det;
    const int t = threadIdx.x, blk = blockIdx.x;
    for (int b = t; b < nbC; b += 256) c[b] = 0;
    const int chunk = (E + NBLK - 1) / NBLK;
    const int e0 = blk * chunk;
    const int e1 = min(E, e0 + chunk);
    const int is64 = detect64(e, e0, e1, t, &det);   // includes syncthreads
    for (int i = e0 + t; i < e1; i += 256) {
        int d = ld_dst(e, E, i, is64);
        atomicAdd(&c[d >> 9], 1);
    }
    __syncthreads();
    for (int b = t; b < nbC; b += 256) cntMat[b * NBLK + blk] = c[b];
}

// ---------- hierarchical exclusive scan over M elements ----------
__global__ __launch_bounds__(256) void k_scan1(const int* __restrict__ in, int* __restrict__ outp,
                                               int* __restrict__ blockSums, int M) {
    __shared__ int sh[256];
    const int t = threadIdx.x;
    const int base = blockIdx.x * 1024 + t * 4;
    int v[4];
#pragma unroll
    for (int i = 0; i < 4; ++i) v[i] = (base + i < M) ? in[base + i] : 0;
    int tot = v[0] + v[1] + v[2] + v[3];
    sh[t] = tot;
    __syncthreads();
    int val = tot;
    for (int o = 1; o < 256; o <<= 1) {
        int x = (t >= o) ? sh[t - o] : 0;
        __syncthreads();
        val += x;
        sh[t] = val;
        __syncthreads();
    }
    int run = val - tot;
#pragma unroll
    for (int i = 0; i < 4; ++i) {
        if (base + i < M) outp[base + i] = run;
        run += v[i];
    }
    if (t == 255) blockSums[blockIdx.x] = val;
}

// scan2 also zeroes BN stats (idle-thread work; runs long before stats accumulate)
__global__ __launch_bounds__(256) void k_scan2(int* __restrict__ blockSums, int nB,
                                               float* __restrict__ stats1, float* __restrict__ stats2) {
    __shared__ int sh[256];
    const int t = threadIdx.x;
    stats1[t] = 0.0f;
    if (t < 128) stats2[t] = 0.0f;
    const int base = t * 4;
    int v[4];
#pragma unroll
    for (int i = 0; i < 4; ++i) v[i] = (base + i < nB) ? blockSums[base + i] : 0;
    int tot = v[0] + v[1] + v[2] + v[3];
    sh[t] = tot;
    __syncthreads();
    int val = tot;
    for (int o = 1; o < 256; o <<= 1) {
        int x = (t >= o) ? sh[t - o] : 0;
        __syncthreads();
        val += x;
        sh[t] = val;
        __syncthreads();
    }
    int run = val - tot;
#pragma unroll
    for (int i = 0; i < 4; ++i) {
        if (base + i < nB) blockSums[base + i] = run;
        run += v[i];
    }
}

// ---------- stage 3: scatter packed (dstLocal,src) into bucket-major pairBuf ----------
__global__ __launch_bounds__(256) void k_bscatter(const int* __restrict__ e,
                                                  const int* __restrict__ ofsMat, const int* __restrict__ blockSums,
                                                  unsigned* __restrict__ pairBuf, int E, int nbC) {
    __shared__ int ofs[512];
    __shared__ int det;
    const int t = threadIdx.x, blk = blockIdx.x;
    for (int b = t; b < nbC; b += 256) {
        int idx = b * NBLK + blk;
        ofs[b] = ofsMat[idx] + blockSums[idx >> 10];
    }
    const int chunk = (E + NBLK - 1) / NBLK;
    const int e0 = blk * chunk;
    const int e1 = min(E, e0 + chunk);
    const int is64 = detect64(e, e0, e1, t, &det);
    for (int i = e0 + t; i < e1; i += 256) {
        int s = ld_src(e, E, i, is64);
        int d = ld_dst(e, E, i, is64);
        int pos = atomicAdd(&ofs[d >> 9], 1);
        pairBuf[pos] = ((unsigned)(d & 511) << 23) | (unsigned)s;
    }
}

// ---------- stage 4: per-bucket fine counting sort; writes csrSrc, rowPtr, cnt, dinv ----------
__global__ __launch_bounds__(256) void k_fsort(const unsigned* __restrict__ pairBuf, const int* __restrict__ ofsMat,
                                               const int* __restrict__ blockSums,
                                               int* __restrict__ csrSrc, int* __restrict__ rowPtr,
                                               int* __restrict__ cnt, float* __restrict__ dinv,
                                               int E, int N, int nbC) {
    __shared__ int hist[512];
    __shared__ int lofs[512];
    __shared__ int sc[256];
    const int t = threadIdx.x, b = blockIdx.x;
    const int i0 = b * NBLK;
    const int lo = ofsMat[i0] + blockSums[i0 >> 10];
    int hi = E;
    if (b + 1 < nbC) {
        const int i1 = (b + 1) * NBLK;
        hi = ofsMat[i1] + blockSums[i1 >> 10];
    }
    hist[t] = 0; hist[t + 256] = 0;
    __syncthreads();
    for (int i = lo + t; i < hi; i += 256) atomicAdd(&hist[pairBuf[i] >> 23], 1);
    __syncthreads();
    int v0 = hist[2 * t], v1 = hist[2 * t + 1];
    int tot = v0 + v1;
    sc[t] = tot;
    __syncthreads();
    int val = tot;
    for (int o = 1; o < 256; o <<= 1) {
        int x = (t >= o) ? sc[t - o] : 0;
        __syncthreads();
        val += x;
        sc[t] = val;
        __syncthreads();
    }
    int excl = val - tot;
    const int d0 = b * 512 + 2 * t;
    const int d1 = d0 + 1;
    lofs[2 * t] = lo + excl;
    lofs[2 * t + 1] = lo + excl + v0;
    if (d0 < N) { rowPtr[d0] = lo + excl;      cnt[d0] = v0; dinv[d0] = rsqrtf((float)(v0 + 1)); }
    if (d1 < N) { rowPtr[d1] = lo + excl + v0; cnt[d1] = v1; dinv[d1] = rsqrtf((float)(v1 + 1)); }
    __syncthreads();
    for (int i = lo + t; i < hi; i += 256) {
        unsigned p = pairBuf[i];
        int dL = p >> 23;
        int s = (int)(p & 0x7FFFFFu);
        int pos = atomicAdd(&lofs[dL], 1);
        csrSrc[pos] = s;
    }
}

// ---------- GEMM1 (MFMA fp16): hs1 = (x @ W1) * dinv[row] ----------
__global__ __launch_bounds__(256, 2) void k_gemm1(const float* __restrict__ x, const float* __restrict__ W,
                                                  const float* __restrict__ dinv,
                                                  _Float16* __restrict__ hs1, int N) {
    __shared__ _Float16 Ws[128][136];
    __shared__ _Float16 xs[128][136];
    const int t = threadIdx.x;
    const int row0 = blockIdx.x * 128;

#pragma unroll
    for (int i = 0; i < 16; ++i) {
        int j = t + i * 256;
        int k = j >> 5, c = (j & 31) << 2;
        float4 v = ((const float4*)W)[j];
        union { _Float16 h[4]; uint2 u; } p;
        p.h[0] = (_Float16)v.x; p.h[1] = (_Float16)v.y; p.h[2] = (_Float16)v.z; p.h[3] = (_Float16)v.w;
        *(uint2*)&Ws[k][c] = p.u;
    }
#pragma unroll
    for (int i = 0; i < 16; ++i) {
        int j = t + i * 256;
        int r = j >> 5, c = (j & 31) << 2;
        int gr = row0 + r;
        float4 v = make_float4(0.f, 0.f, 0.f, 0.f);
        if (gr < N) v = *(const float4*)&x[(size_t)gr * 128 + c];
        union { _Float16 h[4]; uint2 u; } p;
        p.h[0] = (_Float16)v.x; p.h[1] = (_Float16)v.y; p.h[2] = (_Float16)v.z; p.h[3] = (_Float16)v.w;
        *(uint2*)&xs[r][c] = p.u;
    }
    __syncthreads();

    const int w = t >> 6, l = t & 63;
    const int wm = w >> 1, wn = w & 1;
    const int l15 = l & 15, lg = l >> 4;

    f16x8 bfr[4][4];   // [nt][ks]
#pragma unroll
    for (int nt = 0; nt < 4; ++nt)
#pragma unroll
        for (int ks = 0; ks < 4; ++ks) {
            int col = wn * 64 + nt * 16 + l15;
            int kb = ks * 32 + lg * 8;
            f16x8 b;
#pragma unroll
            for (int j = 0; j < 8; ++j) b[j] = Ws[kb + j][col];
            bfr[nt][ks] = b;
        }

    f32x4 acc[4][4];
#pragma unroll
    for (int mt = 0; mt < 4; ++mt)
#pragma unroll
        for (int nt = 0; nt < 4; ++nt) acc[mt][nt] = (f32x4)(0.f);

#pragma unroll
    for (int mt = 0; mt < 4; ++mt) {
        const int r = wm * 64 + mt * 16 + l15;
        f16x8 afr[4];
#pragma unroll
        for (int ks = 0; ks < 4; ++ks) afr[ks] = *(const f16x8*)&xs[r][ks * 32 + lg * 8];
#pragma unroll
        for (int nt = 0; nt < 4; ++nt)
#pragma unroll
            for (int ks = 0; ks < 4; ++ks)
                acc[mt][nt] = __builtin_amdgcn_mfma_f32_16x16x32_f16(afr[ks], bfr[nt][ks], acc[mt][nt], 0, 0, 0);
    }

#pragma unroll
    for (int mt = 0; mt < 4; ++mt) {
        const int rbase = row0 + wm * 64 + mt * 16 + lg * 4;
#pragma unroll
        for (int rr = 0; rr < 4; ++rr) {
            int gr = rbase + rr;
            if (gr < N) {
                float dv = dinv[gr];
#pragma unroll
                for (int nt = 0; nt < 4; ++nt) {
                    int col = wn * 64 + nt * 16 + l15;
                    hs1[(size_t)gr * 128 + col] = (_Float16)(acc[mt][nt][rr] * dv);
                }
            }
        }
    }
}

// ---------- gather128: wave per node, lane = half2 slot; 16/8/4/1 unroll cascade ----------
__global__ __launch_bounds__(256) void k_gather128(const int* __restrict__ csrSrc, const int* __restrict__ rowPtr,
                                                   const int* __restrict__ cnt, const float* __restrict__ dinv,
                                                   const __half2* __restrict__ hs, __half2* __restrict__ agg, int N) {
    int wv = (blockIdx.x * 256 + threadIdx.x) >> 6;
    if (wv >= N) return;
    const int d = __builtin_amdgcn_readfirstlane(wv);
    const int lane = threadIdx.x & 63;
    const size_t fo = (size_t)d * 64 + lane;
    float2 acc = __half22float2(hs[fo]);   // self loop
    const int start = __builtin_amdgcn_readfirstlane(rowPtr[d]);
    const int c = __builtin_amdgcn_readfirstlane(cnt[d]);
    const int* __restrict__ p = csrSrc + start;
    int j = 0;
    for (; j + 15 < c; j += 16) {   // 16 row-loads in flight
        int s[16];
#pragma unroll
        for (int u = 0; u < 16; ++u) s[u] = p[j + u];
        float2 v[16];
#pragma unroll
        for (int u = 0; u < 16; ++u) v[u] = __half22float2(hs[(size_t)s[u] * 64 + lane]);
#pragma unroll
        for (int u = 0; u < 16; ++u) { acc.x += v[u].x; acc.y += v[u].y; }
    }
    for (; j + 7 < c; j += 8) {
        float2 v[8];
#pragma unroll
        for (int u = 0; u < 8; ++u) v[u] = __half22float2(hs[(size_t)p[j + u] * 64 + lane]);
#pragma unroll
        for (int u = 0; u < 8; ++u) { acc.x += v[u].x; acc.y += v[u].y; }
    }
    for (; j + 3 < c; j += 4) {
        float2 v[4];
#pragma unroll
        for (int u = 0; u < 4; ++u) v[u] = __half22float2(hs[(size_t)p[j + u] * 64 + lane]);
#pragma unroll
        for (int u = 0; u < 4; ++u) { acc.x += v[u].x; acc.y += v[u].y; }
    }
    for (; j < c; ++j) {
        float2 v = __half22float2(hs[(size_t)p[j] * 64 + lane]);
        acc.x += v.x; acc.y += v.y;
    }
    const float wgt = dinv[d];
    agg[fo] = __floats2half2_rn(acc.x * wgt, acc.y * wgt);
}

// ---------- gather64: 8 lane-groups per neighbor row (128B), dwordx4 loads ----------
__global__ __launch_bounds__(256) void k_gather64(const int* __restrict__ csrSrc, const int* __restrict__ rowPtr,
                                                  const int* __restrict__ cnt, const float* __restrict__ dinv,
                                                  const __half2* __restrict__ hs, __half2* __restrict__ agg, int N) {
    int wv = (blockIdx.x * 256 + threadIdx.x) >> 6;
    if (wv >= N) return;
    const int d = __builtin_amdgcn_readfirstlane(wv);
    const int l = threadIdx.x & 63;
    const int g = l >> 3, f = l & 7;   // 8 groups of 8 lanes; row = 32 half2 = 8 lanes x 16B

    float2 acc[4];
    if (g == 0) {
        union { uint4 u; __half2 h[4]; } v;
        v.u = *(const uint4*)&hs[(size_t)d * 32 + f * 4];
#pragma unroll
        for (int i = 0; i < 4; ++i) acc[i] = __half22float2(v.h[i]);
    } else {
#pragma unroll
        for (int i = 0; i < 4; ++i) acc[i] = make_float2(0.f, 0.f);
    }

    const int start = __builtin_amdgcn_readfirstlane(rowPtr[d]);
    const int c = __builtin_amdgcn_readfirstlane(cnt[d]);
    const int* __restrict__ p = csrSrc + start;
    int j = 0;
    for (; j + 15 < c; j += 16) {   // 16 neighbors: 2 uint4 loads in flight per lane
        int s0 = p[j + g], s1 = p[j + 8 + g];
        union { uint4 u; __half2 h[4]; } v0, v1;
        v0.u = *(const uint4*)&hs[(size_t)s0 * 32 + f * 4];
        v1.u = *(const uint4*)&hs[(size_t)s1 * 32 + f * 4];
#pragma unroll
        for (int i = 0; i < 4; ++i) {
            float2 a = __half22float2(v0.h[i]);
            float2 b = __half22float2(v1.h[i]);
            acc[i].x += a.x + b.x;
            acc[i].y += a.y + b.y;
        }
    }
    for (; j < c; j += 8) {         // predicated tail, 8 neighbors at a time
        int idx = j + g;
        if (idx < c) {
            union { uint4 u; __half2 h[4]; } v;
            v.u = *(const uint4*)&hs[(size_t)p[idx] * 32 + f * 4];
#pragma unroll
            for (int i = 0; i < 4; ++i) {
                float2 a = __half22float2(v.h[i]);
                acc[i].x += a.x;
                acc[i].y += a.y;
            }
        }
    }

#pragma unroll
    for (int i = 0; i < 4; ++i) {
        acc[i].x += __shfl_xor(acc[i].x, 8);
        acc[i].y += __shfl_xor(acc[i].y, 8);
        acc[i].x += __shfl_xor(acc[i].x, 16);
        acc[i].y += __shfl_xor(acc[i].y, 16);
        acc[i].x += __shfl_xor(acc[i].x, 32);
        acc[i].y += __shfl_xor(acc[i].y, 32);
    }

    if (g == 0) {
        const float wgt = dinv[d];
        union { uint4 u; __half2 h[4]; } o;
#pragma unroll
        for (int i = 0; i < 4; ++i) o.h[i] = __floats2half2_rn(acc[i].x * wgt, acc[i].y * wgt);
        *(uint4*)&agg[(size_t)d * 32 + f * 4] = o.u;
    }
}

// ---------- BN stats from fp16 agg: per-feature sum & sumsq ----------
template <int F>
__global__ __launch_bounds__(256) void k_stats_h(const __half2* __restrict__ a, float* __restrict__ stats, int N) {
    const int S = F / 2;
    const int t = threadIdx.x;
    const int slot = t & (S - 1);
    const int sub = t / S;
    const int rpb = 256 / S;
    float sx = 0.f, sy = 0.f, qx = 0.f, qy = 0.f;
    for (int r = blockIdx.x * rpb + sub; r < N; r += gridDim.x * rpb) {
        float2 v = __half22float2(a[(size_t)r * S + slot]);
        sx += v.x; sy += v.y;
        qx += v.x * v.x; qy += v.y * v.y;
    }
    __shared__ float l0[256], l1[256], l2[256], l3[256];
    l0[t] = sx; l1[t] = sy; l2[t] = qx; l3[t] = qy;
    __syncthreads();
    if (t < S) {
#pragma unroll
        for (int i = 1; i < rpb; ++i) {
            sx += l0[t + i * S]; sy += l1[t + i * S];
            qx += l2[t + i * S]; qy += l3[t + i * S];
        }
        atomicAdd(&stats[2 * t], sx);
        atomicAdd(&stats[2 * t + 1], sy);
        atomicAdd(&stats[F + 2 * t], qx);
        atomicAdd(&stats[F + 2 * t + 1], qy);
    }
}

// ---------- GEMM2 (MFMA fp16): hs2 = (relu(bn(agg1)) @ W2) * dinv; BN params computed in-block ----------
__global__ __launch_bounds__(256, 2) void k_gemm2(const __half* __restrict__ a_in, const float* __restrict__ W,
                                                  const float* __restrict__ stats, const float* __restrict__ g,
                                                  const float* __restrict__ be, const float* __restrict__ dinv,
                                                  _Float16* __restrict__ hs2, int N) {
    __shared__ _Float16 Ws[128][72];
    __shared__ _Float16 xs[128][136];
    __shared__ float ssl[256];   // scale[128], shift[128]
    const int t = threadIdx.x;
    const int row0 = blockIdx.x * 128;

    if (t < 128) {
        float invN = 1.0f / (float)N;
        float mean = stats[t] * invN;
        float var = fmaxf(stats[128 + t] * invN - mean * mean, 0.f);
        float scale = g[t] * rsqrtf(var + BN_EPS);
        ssl[t] = scale;
        ssl[128 + t] = be[t] - mean * scale;
    }

#pragma unroll
    for (int i = 0; i < 8; ++i) {
        int j = t + i * 256;
        int k = j >> 4, c = (j & 15) << 2;
        float4 v = ((const float4*)W)[j];
        union { _Float16 h[4]; uint2 u; } p;
        p.h[0] = (_Float16)v.x; p.h[1] = (_Float16)v.y; p.h[2] = (_Float16)v.z; p.h[3] = (_Float16)v.w;
        *(uint2*)&Ws[k][c] = p.u;
    }
    __syncthreads();   // ssl ready

#pragma unroll
    for (int i = 0; i < 16; ++i) {
        int j = t + i * 256;
        int r = j >> 5, c = (j & 31) << 2;
        int gr = row0 + r;
        float4 v = make_float4(0.f, 0.f, 0.f, 0.f);
        if (gr < N) {
            union { uint2 u; __half2 h[2]; } iv;
            iv.u = *(const uint2*)&a_in[(size_t)gr * 128 + c];
            float2 v01 = __half22float2(iv.h[0]);
            float2 v23 = __half22float2(iv.h[1]);
            float4 sc = *(const float4*)&ssl[c];
            float4 sh = *(const float4*)&ssl[128 + c];
            v.x = fmaxf(0.f, fmaf(v01.x, sc.x, sh.x));
            v.y = fmaxf(0.f, fmaf(v01.y, sc.y, sh.y));
            v.z = fmaxf(0.f, fmaf(v23.x, sc.z, sh.z));
            v.w = fmaxf(0.f, fmaf(v23.y, sc.w, sh.w));
        }
        union { _Float16 h[4]; uint2 u; } p;
        p.h[0] = (_Float16)v.x; p.h[1] = (_Float16)v.y; p.h[2] = (_Float16)v.z; p.h[3] = (_Float16)v.w;
        *(uint2*)&xs[r][c] = p.u;
    }
    __syncthreads();

    const int w = t >> 6, l = t & 63;
    const int wm = w >> 1, wn = w & 1;
    const int l15 = l & 15, lg = l >> 4;

    f16x8 bfr[2][4];
#pragma unroll
    for (int nt = 0; nt < 2; ++nt)
#pragma unroll
        for (int ks = 0; ks < 4; ++ks) {
            int col = wn * 32 + nt * 16 + l15;
            int kb = ks * 32 + lg * 8;
            f16x8 b;
#pragma unroll
            for (int j = 0; j < 8; ++j) b[j] = Ws[kb + j][col];
            bfr[nt][ks] = b;
        }

    f32x4 acc[4][2];
#pragma unroll
    for (int mt = 0; mt < 4; ++mt)
#pragma unroll
        for (int nt = 0; nt < 2; ++nt) acc[mt][nt] = (f32x4)(0.f);

#pragma unroll
    for (int mt = 0; mt < 4; ++mt) {
        const int r = wm * 64 + mt * 16 + l15;
        f16x8 afr[4];
#pragma unroll
        for (int ks = 0; ks < 4; ++ks) afr[ks] = *(const f16x8*)&xs[r][ks * 32 + lg * 8];
#pragma unroll
        for (int nt = 0; nt < 2; ++nt)
#pragma unroll
            for (int ks = 0; ks < 4; ++ks)
                acc[mt][nt] = __builtin_amdgcn_mfma_f32_16x16x32_f16(afr[ks], bfr[nt][ks], acc[mt][nt], 0, 0, 0);
    }

#pragma unroll
    for (int mt = 0; mt < 4; ++mt) {
        const int rbase = row0 + wm * 64 + mt * 16 + lg * 4;
#pragma unroll
        for (int rr = 0; rr < 4; ++rr) {
            int gr = rbase + rr;
            if (gr < N) {
                float dv = dinv[gr];
#pragma unroll
                for (int nt = 0; nt < 2; ++nt) {
                    int col = wn * 32 + nt * 16 + l15;
                    hs2[(size_t)gr * 64 + col] = (_Float16)(acc[mt][nt][rr] * dv);
                }
            }
        }
    }
}

// ---------- final: out = relu(bn(agg2)) @ Wf + bf; BN params computed in-block ----------
__global__ __launch_bounds__(256) void k_final(const __half* __restrict__ a_in, const float* __restrict__ stats,
                                               const float* __restrict__ g, const float* __restrict__ be,
                                               const float* __restrict__ Wf, const float* __restrict__ bf,
                                               float* __restrict__ out, int N) {
    __shared__ float buf[256][65];
    __shared__ float ssl[128];   // scale[64], shift[64]
    const int t = threadIdx.x;
    const int row0 = blockIdx.x * 256;

    if (t < 64) {
        float invN = 1.0f / (float)N;
        float mean = stats[t] * invN;
        float var = fmaxf(stats[64 + t] * invN - mean * mean, 0.f);
        float scale = g[t] * rsqrtf(var + BN_EPS);
        ssl[t] = scale;
        ssl[64 + t] = be[t] - mean * scale;
    }
    __syncthreads();

#pragma unroll
    for (int i = 0; i < 16; ++i) {
        int j = t + i * 256;
        int r = j >> 4;
        int k = (j & 15) << 2;
        float4 v = make_float4(0.f, 0.f, 0.f, 0.f);
        int gr = row0 + r;
        if (gr < N) {
            union { uint2 u; __half2 h[2]; } iv;
            iv.u = *(const uint2*)&a_in[(size_t)gr * 64 + k];
            float2 v01 = __half22float2(iv.h[0]);
            float2 v23 = __half22float2(iv.h[1]);
            float4 sc = *(const float4*)&ssl[k];
            float4 sh = *(const float4*)&ssl[64 + k];
            v.x = fmaxf(0.f, fmaf(v01.x, sc.x, sh.x));
            v.y = fmaxf(0.f, fmaf(v01.y, sc.y, sh.y));
            v.z = fmaxf(0.f, fmaf(v23.x, sc.z, sh.z));
            v.w = fmaxf(0.f, fmaf(v23.y, sc.w, sh.w));
        }
        buf[r][k + 0] = v.x; buf[r][k + 1] = v.y; buf[r][k + 2] = v.z; buf[r][k + 3] = v.w;
    }
    __syncthreads();

    int gr = row0 + t;
    if (gr < N) {
        float a0 = 0.f, a1 = 0.f;
        for (int k = 0; k < 64; ++k) {
            float v = buf[t][k];
            a0 = fmaf(v, Wf[2 * k + 0], a0);
            a1 = fmaf(v, Wf[2 * k + 1], a1);
        }
        out[(size_t)gr * 2 + 0] = a0 + bf[0];
        out[(size_t)gr * 2 + 1] = a1 + bf[1];
    }
}

extern "C" void kernel_launch(void* const* d_in, const int* in_sizes, int n_in,
                              void* d_out, int out_size, void* d_ws, size_t ws_size,
                              hipStream_t stream) {
    const float* x   = (const float*)d_in[0];
    const int*   ei  = (const int*)d_in[1];
    const float* W1  = (const float*)d_in[2];
    const float* g1  = (const float*)d_in[4];
    const float* be1 = (const float*)d_in[5];
    const float* W2  = (const float*)d_in[6];
    const float* g2  = (const float*)d_in[8];
    const float* be2 = (const float*)d_in[9];
    const float* Wf  = (const float*)d_in[10];
    const float* bf  = (const float*)d_in[11];
    float* out = (float*)d_out;

    const int N = in_sizes[0] / 128;
    const int E = in_sizes[1] / 2;
    const int nbC = (N + 511) >> 9;          // coarse buckets of 512 dsts
    const int M = nbC * NBLK;                // count-matrix size
    const int nBs = (M + 1023) / 1024;       // scan blocks (<=1024 fits k_scan2)

    float* fws = (float*)d_ws;
    float* stats1 = fws + 64;            // 256
    float* stats2 = fws + 320;           // 128
    int*   blockSums = (int*)(fws + 832);// up to 1024

    const size_t Na = (size_t)((N + 255) & ~255);
    const size_t Ea = (size_t)((E + 255) & ~255);
    const size_t Ma = (size_t)((M + 255) & ~255);
    size_t off = 2048;
    int*   cnt    = (int*)(fws + off);  off += Na;
    int*   rowPtr = (int*)(fws + off);  off += Na;
    float* dinv   = fws + off;          off += Na;
    int*   cntMat = (int*)(fws + off);  off += Ma;
    int*   ofsMat = (int*)(fws + off);  off += Ma;
    int*   csrSrc = (int*)(fws + off);  off += Ea;
    _Float16* hs1 = (_Float16*)(fws + off);                // N*128 fp16
    __half*  agg1 = (__half*)(fws + off + (size_t)N * 64); // N*128 fp16
    _Float16* hs2 = hs1;                                   // N*64 fp16 (reuse)
    __half*  agg2 = agg1;                                  // N*64 fp16 (reuse)
    unsigned* pairBuf = (unsigned*)hs1;                    // E u32 (dead before gemm1)

    // atomic-free CSR build (two-level counting sort); per-block int64 self-detection
    k_bcount<<<NBLK, 256, 0, stream>>>(ei, cntMat, E, nbC);
    k_scan1<<<nBs, 256, 0, stream>>>(cntMat, ofsMat, blockSums, M);
    k_scan2<<<1, 256, 0, stream>>>(blockSums, nBs, stats1, stats2);
    k_bscatter<<<NBLK, 256, 0, stream>>>(ei, ofsMat, blockSums, pairBuf, E, nbC);
    k_fsort<<<nbC, 256, 0, stream>>>(pairBuf, ofsMat, blockSums, csrSrc, rowPtr, cnt, dinv, E, N, nbC);

    k_gemm1<<<(N + 127) / 128, 256, 0, stream>>>(x, W1, dinv, hs1, N);
    k_gather128<<<(N * 64 + 255) / 256, 256, 0, stream>>>(csrSrc, rowPtr, cnt, dinv,
                                                          (const __half2*)hs1, (__half2*)agg1, N);
    k_stats_h<128><<<512, 256, 0, stream>>>((const __half2*)agg1, stats1, N);

    k_gemm2<<<(N + 127) / 128, 256, 0, stream>>>(agg1, W2, stats1, g1, be1, dinv, hs2, N);
    k_gather64<<<(N * 64 + 255) / 256, 256, 0, stream>>>(csrSrc, rowPtr, cnt, dinv,
                                                         (const __half2*)hs2, (__half2*)agg2, N);
    k_stats_h<64><<<512, 256, 0, stream>>>((const __half2*)agg2, stats2, N);

    k_final<<<(N + 255) / 256, 256, 0, stream>>>(agg2, stats2, g2, be2, Wf, bf, out, N);
}